// Round 4
// baseline (457.955 us; speedup 1.0000x reference)
//
#include <hip/hip_runtime.h>
#include <hip/hip_bf16.h>

#define D  128
#define KN 32

typedef __attribute__((ext_vector_type(8))) short bf16x8;
typedef __attribute__((ext_vector_type(4))) float f32x4;

union bfu { bf16x8 v; unsigned int u[4]; };

static __device__ __forceinline__ unsigned short f2bf(float f) {
    union { float f; unsigned int u; } v; v.f = f;
    unsigned int u = v.u;
    u += 0x7fff + ((u >> 16) & 1);   // round-to-nearest-even
    return (unsigned short)(u >> 16);
}
static __device__ __forceinline__ float bf2f(unsigned short h) {
    union { float f; unsigned int u; } v; v.u = ((unsigned int)h) << 16;
    return v.f;
}

// One-shot: transpose+convert W1 halves and W2 into bf16 [col][k] layouts.
__global__ __launch_bounds__(256) void wt_kernel(
    const float* __restrict__ W1, const float* __restrict__ W2,
    unsigned short* __restrict__ W1Tt, unsigned short* __restrict__ W1Tb,
    unsigned short* __restrict__ W2T)
{
    int idx = blockIdx.x * 256 + threadIdx.x;
    if (idx < D * D) {
        int col = idx >> 7, e = idx & 127;
        W1Tt[col * D + e] = f2bf(W1[e * D + col]);
        W1Tb[col * D + e] = f2bf(W1[(D + e) * D + col]);
        W2T [col * D + e] = f2bf(W2[e * D + col]);
    }
}

// Producer: blocks [0,ebBlocks): pure stream-convert emb fp32 -> EB bf16.
// Blocks [ebBlocks,..): Q = emb[vnodes]@W1bot + b1, stored FP32 (10 MB).
// P1 is GONE: layer-1 for neighbors is recomputed in the node kernel.
__global__ __launch_bounds__(256) void ebq_kernel(
    const float* __restrict__ emb, const int* __restrict__ vnodes,
    int NV, int NN, int ebBlocks,
    const unsigned short* __restrict__ W1Tb, const float* __restrict__ b1,
    unsigned short* __restrict__ EB, float* __restrict__ Qf)
{
    __shared__ unsigned short sA[128][136];
    const int tid = threadIdx.x;

    if ((int)blockIdx.x < ebBlocks) {
        const long base  = (long)blockIdx.x * 16384;
        const long total = (long)NV * D;
#pragma unroll
        for (int j = 0; j < 8; ++j) {
            long p = base + j * 2048 + tid * 8;
            if (p < total) {
                float4 f0 = *(const float4*)(emb + p);
                float4 f1 = *(const float4*)(emb + p + 4);
                bf16x8 o;
                o[0] = (short)f2bf(f0.x); o[1] = (short)f2bf(f0.y);
                o[2] = (short)f2bf(f0.z); o[3] = (short)f2bf(f0.w);
                o[4] = (short)f2bf(f1.x); o[5] = (short)f2bf(f1.y);
                o[6] = (short)f2bf(f1.z); o[7] = (short)f2bf(f1.w);
                *(bf16x8*)(EB + p) = o;
            }
        }
        return;
    }

    // ---- Q GEMM part ----
    const int bi   = blockIdx.x - ebBlocks;
    const int lane = tid & 63;
    const int w    = tid >> 6;
    const int m    = lane & 15, q = lane >> 4;
    const int r0   = bi * 128;

#pragma unroll
    for (int i = 0; i < 16; ++i) {
        int e = tid + 256 * i;
        int row = e >> 5, c4 = (e & 31) << 2;
        int r = r0 + row; if (r > NN - 1) r = NN - 1;
        int vr = vnodes[r];
        const float4 f = *(const float4*)(emb + (long)vr * D + c4);
        ushort4 h;
        h.x = f2bf(f.x); h.y = f2bf(f.y); h.z = f2bf(f.z); h.w = f2bf(f.w);
        *(ushort4*)(&sA[row][c4]) = h;
    }
    __syncthreads();

    bf16x8 Bf[2][4];
#pragma unroll
    for (int nt = 0; nt < 2; ++nt)
#pragma unroll
        for (int kk = 0; kk < 4; ++kk)
            Bf[nt][kk] = *(const bf16x8*)(W1Tb + (32 * w + 16 * nt + m) * D + kk * 32 + q * 8);
    float bv[2];
#pragma unroll
    for (int nt = 0; nt < 2; ++nt) bv[nt] = b1[32 * w + 16 * nt + m];

    f32x4 acc[8][2];
#pragma unroll
    for (int mt = 0; mt < 8; ++mt)
#pragma unroll
        for (int nt = 0; nt < 2; ++nt) acc[mt][nt] = (f32x4){0.f, 0.f, 0.f, 0.f};

#pragma unroll
    for (int kk = 0; kk < 4; ++kk) {
#pragma unroll
        for (int mt = 0; mt < 8; ++mt) {
            bf16x8 a = *(const bf16x8*)(&sA[16 * mt + m][kk * 32 + q * 8]);
            acc[mt][0] = __builtin_amdgcn_mfma_f32_16x16x32_bf16(a, Bf[0][kk], acc[mt][0], 0, 0, 0);
            acc[mt][1] = __builtin_amdgcn_mfma_f32_16x16x32_bf16(a, Bf[1][kk], acc[mt][1], 0, 0, 0);
        }
    }

    // C layout: col = lane&15, row = (lane>>4)*4 + r. Store fp32 Q.
#pragma unroll
    for (int mt = 0; mt < 8; ++mt)
#pragma unroll
        for (int nt = 0; nt < 2; ++nt) {
            int col = 32 * w + 16 * nt + m;
#pragma unroll
            for (int r = 0; r < 4; ++r) {
                int row = r0 + 16 * mt + 4 * q + r;
                if (row < NN) Qf[(long)row * D + col] = acc[mt][nt][r] + bv[nt];
            }
        }
}

// Fused per-node kernel: one node per wave, zero barriers in the node loop.
// Per node: gather 32 EB rows ONCE into B-layout fragments; layer-1 is the
// operand-swapped GEMM D1 = W1top^T . EB^T (A=weights from LDS, B=gathered
// frags); add Q[node] (fp32), relu; in-register lane-transpose to layer-2's
// B-operand; D2 = W2^T . H1; scores+softmax in-wave; final aggregation reuses
// the SAME EB fragments (no second gather, no P1 array at all).
// Traffic per node: 8KB EB + 0.5KB Q + 128B idx + 0.5KB out  (was 16.75KB).
__global__ __launch_bounds__(256, 2) void node_kernel(
    const unsigned short* __restrict__ EB, const int* __restrict__ nidx,
    const float* __restrict__ Qf,
    const unsigned short* __restrict__ W1Tt, const unsigned short* __restrict__ W2T,
    const float* __restrict__ b2, const float* __restrict__ W3,
    const float* __restrict__ b3,
    float* __restrict__ out, int NN)
{
    __shared__ bf16x8 sA1[2048];     // W1top^T A-frags, frag-linear, 32 KB
    __shared__ bf16x8 sA2[2048];     // W2^T    A-frags, frag-linear, 32 KB
    __shared__ float  sb2f[128], sw3f[128];

    const int tid  = threadIdx.x;
    const int lane = tid & 63;
    const int w    = tid >> 6;
    const int m    = lane & 15, q = lane >> 4;

    // stage A-frags: slot fi = kk*8+mt; lane l=(mm,qq) holds
    // W^T[(16mt+mm)*128 + kk*32 + qq*8 .. +7]  (A: row=lane&15, k=(lane>>4)*8+h)
#pragma unroll
    for (int i = 0; i < 8; ++i) {
        int f  = tid + 256 * i;
        int fi = f >> 6, l = f & 63;
        int kk = fi >> 3, mt = fi & 7;
        int off = ((16 * mt + (l & 15)) << 7) + kk * 32 + (l >> 4) * 8;
        sA1[f] = *(const bf16x8*)(W1Tt + off);
        sA2[f] = *(const bf16x8*)(W2T + off);
    }
    if (tid < 128) { sb2f[tid] = b2[tid]; sw3f[tid] = W3[tid]; }
    __syncthreads();

    const float b3s = b3[0];
    const int stride = gridDim.x << 2;
    int node = (blockIdx.x << 2) + w;
    if (node >= NN) return;

    // ---- prologue: gather EB fragments for the first node ----
    bf16x8 ebC[2][4], ebN[2][4];
    {
        int iv = (lane < KN) ? nidx[node * KN + lane] : 0;
        const long i0 = __shfl(iv, m);        // neighbor n = m
        const long i1 = __shfl(iv, 16 + m);   // neighbor n = 16+m
        const unsigned short* p0 = EB + i0 * D + q * 8;
        const unsigned short* p1 = EB + i1 * D + q * 8;
#pragma unroll
        for (int kk = 0; kk < 4; ++kk) {
            ebC[0][kk] = *(const bf16x8*)(p0 + kk * 32);
            ebC[1][kk] = *(const bf16x8*)(p1 + kk * 32);
        }
    }

    for (; node < NN; node += stride) {
        // Q row for current node: qv[mt][r] = Q[node][16mt+4q+r]
        // (first use is after 64 MFMA -> latency hidden)
        f32x4 qv[8];
#pragma unroll
        for (int mt = 0; mt < 8; ++mt)
            qv[mt] = *(const f32x4*)(Qf + (long)node * D + 16 * mt + 4 * q);

        const int noden = node + stride;
        const bool more = noden < NN;
        int ivn = (more && lane < KN) ? nidx[noden * KN + lane] : 0;

        // ---- layer 1: D1[d][n] = sum_e W1top[e][d] * EB[n][e] ----
        f32x4 acc1[8][2];
#pragma unroll
        for (int mt = 0; mt < 8; ++mt) {
            acc1[mt][0] = (f32x4){0.f, 0.f, 0.f, 0.f};
            acc1[mt][1] = (f32x4){0.f, 0.f, 0.f, 0.f};
        }
#pragma unroll
        for (int kk = 0; kk < 4; ++kk)
#pragma unroll
            for (int mt = 0; mt < 8; ++mt) {
                bf16x8 a = sA1[((kk << 3) + mt) * 64 + lane];
                acc1[mt][0] = __builtin_amdgcn_mfma_f32_16x16x32_bf16(a, ebC[0][kk], acc1[mt][0], 0, 0, 0);
                acc1[mt][1] = __builtin_amdgcn_mfma_f32_16x16x32_bf16(a, ebC[1][kk], acc1[mt][1], 0, 0, 0);
            }

        // ---- H1 = relu(acc1 + qv), packed to bf16 pairs ----
        // hp[mt'][nt][p]: pair p holds d = 16mt'+4q'+{2p, 2p+1} for this lane's q'
        unsigned int hp[8][2][2];
#pragma unroll
        for (int mt = 0; mt < 8; ++mt)
#pragma unroll
            for (int nt = 0; nt < 2; ++nt) {
                float v0 = acc1[mt][nt][0] + qv[mt][0]; v0 = v0 > 0.f ? v0 : 0.f;
                float v1 = acc1[mt][nt][1] + qv[mt][1]; v1 = v1 > 0.f ? v1 : 0.f;
                float v2 = acc1[mt][nt][2] + qv[mt][2]; v2 = v2 > 0.f ? v2 : 0.f;
                float v3 = acc1[mt][nt][3] + qv[mt][3]; v3 = v3 > 0.f ? v3 : 0.f;
                hp[mt][nt][0] = (unsigned)f2bf(v0) | ((unsigned)f2bf(v1) << 16);
                hp[mt][nt][1] = (unsigned)f2bf(v2) | ((unsigned)f2bf(v3) << 16);
            }

        // ---- lane-transpose C-layout -> B-layout for layer 2 ----
        // Dest lane (m,q), frag (nt,kk), elem h needs H1[32kk+8q+h][16nt+m],
        // held at lane (m, q'=2(q&1)+(h>>2)) as hv[mt'=2kk+(q>>1)][nt][h&3].
        const int srcLo = ((q & 1) << 5) + m;   // lane with q' = 2(q&1)
        const int srcHi = srcLo + 16;           // lane with q' = 2(q&1)+1
        const bool hiSel = (q & 2) != 0;        // selects mt' = 2kk+1
        bfu B2[2][4];
#pragma unroll
        for (int nt = 0; nt < 2; ++nt)
#pragma unroll
            for (int kk = 0; kk < 4; ++kk) {
                unsigned aa0 = __shfl(hp[2 * kk][nt][0], srcLo);
                unsigned bb0 = __shfl(hp[2 * kk + 1][nt][0], srcLo);
                unsigned aa1 = __shfl(hp[2 * kk][nt][1], srcLo);
                unsigned bb1 = __shfl(hp[2 * kk + 1][nt][1], srcLo);
                unsigned cc0 = __shfl(hp[2 * kk][nt][0], srcHi);
                unsigned dd0 = __shfl(hp[2 * kk + 1][nt][0], srcHi);
                unsigned cc1 = __shfl(hp[2 * kk][nt][1], srcHi);
                unsigned dd1 = __shfl(hp[2 * kk + 1][nt][1], srcHi);
                B2[nt][kk].u[0] = hiSel ? bb0 : aa0;   // h0,h1
                B2[nt][kk].u[1] = hiSel ? bb1 : aa1;   // h2,h3
                B2[nt][kk].u[2] = hiSel ? dd0 : cc0;   // h4,h5
                B2[nt][kk].u[3] = hiSel ? dd1 : cc1;   // h6,h7
            }

        // ---- next-node EB gather (hidden under layer-2 + scores + agg) ----
        if (more) {
            const long i0 = __shfl(ivn, m);
            const long i1 = __shfl(ivn, 16 + m);
            const unsigned short* p0 = EB + i0 * D + q * 8;
            const unsigned short* p1 = EB + i1 * D + q * 8;
#pragma unroll
            for (int kk = 0; kk < 4; ++kk) {
                ebN[0][kk] = *(const bf16x8*)(p0 + kk * 32);
                ebN[1][kk] = *(const bf16x8*)(p1 + kk * 32);
            }
        }

        // ---- layer 2: D2[d2][n] = sum_d1 W2[d1][d2] * H1[d1][n] ----
        f32x4 acc2[8][2];
#pragma unroll
        for (int mt = 0; mt < 8; ++mt) {
            acc2[mt][0] = (f32x4){0.f, 0.f, 0.f, 0.f};
            acc2[mt][1] = (f32x4){0.f, 0.f, 0.f, 0.f};
        }
#pragma unroll
        for (int kk = 0; kk < 4; ++kk)
#pragma unroll
            for (int mt = 0; mt < 8; ++mt) {
                bf16x8 a = sA2[((kk << 3) + mt) * 64 + lane];
                acc2[mt][0] = __builtin_amdgcn_mfma_f32_16x16x32_bf16(a, B2[0][kk].v, acc2[mt][0], 0, 0, 0);
                acc2[mt][1] = __builtin_amdgcn_mfma_f32_16x16x32_bf16(a, B2[1][kk].v, acc2[mt][1], 0, 0, 0);
            }

        // ---- scores: s[n] = sum_d2 relu(acc2+b2)[d2][n] * W3[d2] ----
        float sp0 = 0.f, sp1 = 0.f;
#pragma unroll
        for (int mt = 0; mt < 8; ++mt) {
            f32x4 bb = *(const f32x4*)(&sb2f[16 * mt + 4 * q]);
            f32x4 ww = *(const f32x4*)(&sw3f[16 * mt + 4 * q]);
#pragma unroll
            for (int r = 0; r < 4; ++r) {
                float h0 = acc2[mt][0][r] + bb[r]; h0 = h0 > 0.f ? h0 : 0.f;
                float h1 = acc2[mt][1][r] + bb[r]; h1 = h1 > 0.f ? h1 : 0.f;
                sp0 += h0 * ww[r];
                sp1 += h1 * ww[r];
            }
        }
        sp0 += __shfl_xor(sp0, 16); sp0 += __shfl_xor(sp0, 32);
        sp1 += __shfl_xor(sp1, 16); sp1 += __shfl_xor(sp1, 32);
        const float s0 = sp0 + b3s, s1 = sp1 + b3s;

        // softmax over 32 neighbors: lane holds n=m (s0) and n=16+m (s1)
        float mx = fmaxf(s0, s1);
#pragma unroll
        for (int off = 1; off <= 8; off <<= 1) mx = fmaxf(mx, __shfl_xor(mx, off));
        float e0v = __expf(s0 - mx), e1v = __expf(s1 - mx);
        float sum = e0v + e1v;
#pragma unroll
        for (int off = 1; off <= 8; off <<= 1) sum += __shfl_xor(sum, off);
        const float inv  = 1.f / sum;
        const float att0 = e0v * inv, att1 = e1v * inv;

        // ---- aggregation reusing ebC: out[e] = sum_n att[n]*EB[n][e] ----
        // per-lane partials for its 32 e-values (e = 32kk + 8q + h)
        float pa[32];
#pragma unroll
        for (int kk = 0; kk < 4; ++kk)
#pragma unroll
            for (int h = 0; h < 8; ++h)
                pa[kk * 8 + h] = att0 * bf2f((unsigned short)ebC[0][kk][h])
                               + att1 * bf2f((unsigned short)ebC[1][kk][h]);

        // recursive-halving reduce-scatter across the 16 m-lanes.
        // stage (mask, m-bit): keep half with v_bit == m_bit, compacted low.
        {   // mask 8 (v4 = m3), L=32
            const bool hi = (m & 8) != 0;
#pragma unroll
            for (int j = 0; j < 16; ++j) {
                float sv = hi ? pa[j] : pa[16 + j];
                float rv = __shfl_xor(sv, 8);
                pa[j] = (hi ? pa[16 + j] : pa[j]) + rv;
            }
        }
        {   // mask 4 (v3 = m2), L=16
            const bool hi = (m & 4) != 0;
#pragma unroll
            for (int j = 0; j < 8; ++j) {
                float sv = hi ? pa[j] : pa[8 + j];
                float rv = __shfl_xor(sv, 4);
                pa[j] = (hi ? pa[8 + j] : pa[j]) + rv;
            }
        }
        {   // mask 2 (v2 = m1), L=8
            const bool hi = (m & 2) != 0;
#pragma unroll
            for (int j = 0; j < 4; ++j) {
                float sv = hi ? pa[j] : pa[4 + j];
                float rv = __shfl_xor(sv, 2);
                pa[j] = (hi ? pa[4 + j] : pa[j]) + rv;
            }
        }
        {   // mask 1 (v1 = m0), L=4
            const bool hi = (m & 1) != 0;
#pragma unroll
            for (int j = 0; j < 2; ++j) {
                float sv = hi ? pa[j] : pa[2 + j];
                float rv = __shfl_xor(sv, 1);
                pa[j] = (hi ? pa[2 + j] : pa[j]) + rv;
            }
        }
        // lane (m,q) owns e = (m>>2)*32 + q*8 + (m&3)*2 + {0,1}
        {
            int e0 = ((m >> 2) << 5) + (q << 3) + ((m & 3) << 1);
            float2 o; o.x = pa[0]; o.y = pa[1];
            *(float2*)(out + (long)node * D + e0) = o;
        }

        if (more) {
#pragma unroll
            for (int nt = 0; nt < 2; ++nt)
#pragma unroll
                for (int kk = 0; kk < 4; ++kk) ebC[nt][kk] = ebN[nt][kk];
        }
    }
}

// Correct-but-slow fp32 VALU fallback (only if ws is too small).
__global__ __launch_bounds__(128) void naive_kernel(
    const float* __restrict__ emb, const int* __restrict__ vnodes,
    const int* __restrict__ nidx,
    const float* __restrict__ W1, const float* __restrict__ b1,
    const float* __restrict__ W2, const float* __restrict__ b2,
    const float* __restrict__ W3, const float* __restrict__ b3,
    float* __restrict__ out)
{
    __shared__ float sE[KN + 1][D];
    __shared__ float sH[KN][D];
    __shared__ float sH2[KN][D];
    __shared__ float sS[KN];
    __shared__ float sA2[KN];
    const int node = blockIdx.x, tid = threadIdx.x;

    for (int r = 0; r < KN + 1; ++r) {
        int vr = (r < KN) ? nidx[node * KN + r] : vnodes[node];
        sE[r][tid] = emb[(long)vr * D + tid];
    }
    __syncthreads();
    for (int k = 0; k < KN; ++k) {
        float s = b1[tid];
        for (int e = 0; e < D; ++e) s += sE[k][e]  * W1[e * D + tid];
        for (int e = 0; e < D; ++e) s += sE[KN][e] * W1[(D + e) * D + tid];
        sH[k][tid] = s > 0.f ? s : 0.f;
    }
    __syncthreads();
    for (int k = 0; k < KN; ++k) {
        float s = b2[tid];
        for (int e = 0; e < D; ++e) s += sH[k][e] * W2[e * D + tid];
        sH2[k][tid] = s > 0.f ? s : 0.f;
    }
    __syncthreads();
    if (tid < KN) {
        float s = b3[0];
        for (int e = 0; e < D; ++e) s += sH2[tid][e] * W3[e];
        sS[tid] = s;
    }
    __syncthreads();
    if (tid == 0) {
        float mx = sS[0];
        for (int k = 1; k < KN; ++k) mx = fmaxf(mx, sS[k]);
        float sum = 0.f;
        for (int k = 0; k < KN; ++k) { sA2[k] = __expf(sS[k] - mx); sum += sA2[k]; }
        for (int k = 0; k < KN; ++k) sA2[k] /= sum;
    }
    __syncthreads();
    float a = 0.f;
    for (int k = 0; k < KN; ++k) a += sA2[k] * sE[k][tid];
    out[(long)node * D + tid] = a;
}

extern "C" void kernel_launch(void* const* d_in, const int* in_sizes, int n_in,
                              void* d_out, int out_size, void* d_ws, size_t ws_size,
                              hipStream_t stream) {
    const float* emb    = (const float*)d_in[0];
    const int*   vnodes = (const int*)d_in[1];
    const int*   nidx   = (const int*)d_in[2];
    const float* W1     = (const float*)d_in[3];
    const float* b1     = (const float*)d_in[4];
    const float* W2     = (const float*)d_in[5];
    const float* b2     = (const float*)d_in[6];
    const float* W3     = (const float*)d_in[7];
    const float* b3     = (const float*)d_in[8];
    float* out = (float*)d_out;

    const int NV = in_sizes[0] / D;   // 200000
    const int NN = in_sizes[1];       // 20000

    const size_t q_bytes  = (size_t)NN * D * sizeof(float);
    const size_t eb_bytes = (size_t)NV * D * sizeof(unsigned short);
    const size_t wt_bytes = (size_t)D * D * sizeof(unsigned short);
    const size_t need = q_bytes + eb_bytes + 3 * wt_bytes;

    if (ws_size >= need) {
        float*          Qf   = (float*)d_ws;
        unsigned short* EB   = (unsigned short*)((char*)d_ws + q_bytes);
        unsigned short* W1Tt = EB + (size_t)NV * D;
        unsigned short* W1Tb = W1Tt + (size_t)D * D;
        unsigned short* W2T  = W1Tb + (size_t)D * D;

        const long total = (long)NV * D;
        const int ebBlocks = (int)((total + 16383) / 16384);
        const int qBlocks  = (NN + 127) / 128;

        wt_kernel<<<(D * D + 255) / 256, 256, 0, stream>>>(W1, W2, W1Tt, W1Tb, W2T);
        ebq_kernel<<<ebBlocks + qBlocks, 256, 0, stream>>>(
            emb, vnodes, NV, NN, ebBlocks, W1Tb, b1, EB, Qf);
        node_kernel<<<512, 256, 0, stream>>>(
            EB, nidx, Qf, W1Tt, W2T, b2, W3, b3, out, NN);
    } else {
        naive_kernel<<<NN, D, 0, stream>>>(emb, vnodes, nidx, W1, b1, W2, b2, W3, b3, out);
    }
}

// Round 5
// 292.522 us; speedup vs baseline: 1.5655x; 1.5655x over previous
//
#include <hip/hip_runtime.h>
#include <hip/hip_bf16.h>

#define D  128
#define KN 32

typedef __attribute__((ext_vector_type(8))) short bf16x8;
typedef __attribute__((ext_vector_type(4))) float f32x4;

static __device__ __forceinline__ unsigned short f2bf(float f) {
    union { float f; unsigned int u; } v; v.f = f;
    unsigned int u = v.u;
    u += 0x7fff + ((u >> 16) & 1);   // round-to-nearest-even
    return (unsigned short)(u >> 16);
}
static __device__ __forceinline__ float bf2f(unsigned short h) {
    union { float f; unsigned int u; } v; v.u = ((unsigned int)h) << 16;
    return v.f;
}

// One-shot: transpose+convert W1 halves and W2 into bf16 [col][k] layouts.
__global__ __launch_bounds__(256) void wt_kernel(
    const float* __restrict__ W1, const float* __restrict__ W2,
    unsigned short* __restrict__ W1Tt, unsigned short* __restrict__ W1Tb,
    unsigned short* __restrict__ W2T)
{
    int idx = blockIdx.x * 256 + threadIdx.x;
    if (idx < D * D) {
        int col = idx >> 7, e = idx & 127;
        W1Tt[col * D + e] = f2bf(W1[e * D + col]);
        W1Tb[col * D + e] = f2bf(W1[(D + e) * D + col]);
        W2T [col * D + e] = f2bf(W2[e * D + col]);
    }
}

// Fused P1/Q producer (round-3-verified version: restaged epilogue with
// fully-contiguous 4KB-per-instruction stores for EB, P1 and Q).
// Blocks [0,nvBlocks): P1 = emb@W1top (+ bf16 emb copy EB).
// Blocks [nvBlocks,..): Q = emb[vnodes]@W1bot + b1.
__global__ __launch_bounds__(256) void p1q_kernel(
    const float* __restrict__ emb, const int* __restrict__ vnodes,
    int NV, int NN, int nvBlocks,
    const unsigned short* __restrict__ W1Tt, const unsigned short* __restrict__ W1Tb,
    const float* __restrict__ b1,
    unsigned short* __restrict__ P1, unsigned short* __restrict__ Q,
    unsigned short* __restrict__ EB)
{
    __shared__ unsigned short sA[128][136];

    const int tid  = threadIdx.x;
    const int lane = tid & 63;
    const int w    = tid >> 6;
    const int m    = lane & 15, q = lane >> 4;

    const bool nv = (int)blockIdx.x < nvBlocks;
    const int  bi = nv ? blockIdx.x : blockIdx.x - nvBlocks;
    const int  M  = nv ? NV : NN;
    const unsigned short* WT = nv ? W1Tt : W1Tb;
    const int r0 = bi * 128;

    int maxRows = M - r0; if (maxRows > 128) maxRows = 128;
    const int maxB = maxRows << 8;          // valid bytes in this block's region

    // stage 128 rows fp32->bf16 (coalesced float4 stream / gather)
#pragma unroll
    for (int i = 0; i < 16; ++i) {
        int e = tid + 256 * i;
        int row = e >> 5, c4 = (e & 31) << 2;
        int r = r0 + row; if (r > M - 1) r = M - 1;
        int vr = nv ? r : vnodes[r];
        const float4 f = *(const float4*)(emb + (long)vr * D + c4);
        ushort4 h;
        h.x = f2bf(f.x); h.y = f2bf(f.y); h.z = f2bf(f.z); h.w = f2bf(f.w);
        *(ushort4*)(&sA[row][c4]) = h;
    }
    __syncthreads();

    // EB emission (pre-restage sA): fully-contiguous 4KB per instruction
    if (nv) {
        char* ebBase = (char*)(EB + (long)r0 * D);
#pragma unroll
        for (int j = 0; j < 8; ++j) {
            int p = j * 4096 + tid * 16;
            if (p < maxB) {
                int row = p >> 8, off = (p & 255) >> 1;
                *(bf16x8*)(ebBase + p) = *(const bf16x8*)(&sA[row][off]);
            }
        }
    }

    bf16x8 Bf[2][4];
#pragma unroll
    for (int nt = 0; nt < 2; ++nt)
#pragma unroll
        for (int kk = 0; kk < 4; ++kk)
            Bf[nt][kk] = *(const bf16x8*)(WT + (32 * w + 16 * nt + m) * D + kk * 32 + q * 8);
    float bv[2];
#pragma unroll
    for (int nt = 0; nt < 2; ++nt) bv[nt] = nv ? 0.f : b1[32 * w + 16 * nt + m];

    f32x4 acc[8][2];
#pragma unroll
    for (int mt = 0; mt < 8; ++mt)
#pragma unroll
        for (int nt = 0; nt < 2; ++nt) acc[mt][nt] = (f32x4){0.f, 0.f, 0.f, 0.f};

#pragma unroll
    for (int kk = 0; kk < 4; ++kk) {
#pragma unroll
        for (int mt = 0; mt < 8; ++mt) {
            bf16x8 a = *(const bf16x8*)(&sA[16 * mt + m][kk * 32 + q * 8]);
            acc[mt][0] = __builtin_amdgcn_mfma_f32_16x16x32_bf16(a, Bf[0][kk], acc[mt][0], 0, 0, 0);
            acc[mt][1] = __builtin_amdgcn_mfma_f32_16x16x32_bf16(a, Bf[1][kk], acc[mt][1], 0, 0, 0);
        }
    }

    // ---- restage C into sA, then fully-contiguous 4KB stores ----
    __syncthreads();   // all A-reads + EB-reads of sA complete
    // C/D layout: col=lane&15, row=(lane>>4)*4+reg
#pragma unroll
    for (int mt = 0; mt < 8; ++mt)
#pragma unroll
        for (int nt = 0; nt < 2; ++nt) {
            int col = 32 * w + 16 * nt + m;
#pragma unroll
            for (int r = 0; r < 4; ++r)
                sA[16 * mt + 4 * q + r][col] = f2bf(acc[mt][nt][r] + bv[nt]);
        }
    __syncthreads();
    {
        char* dstBase = (char*)((nv ? P1 : Q) + (long)r0 * D);
#pragma unroll
        for (int j = 0; j < 8; ++j) {
            int p = j * 4096 + tid * 16;
            if (p < maxB) {
                int row = p >> 8, off = (p & 255) >> 1;
                *(bf16x8*)(dstBase + p) = *(const bf16x8*)(&sA[row][off]);
            }
        }
    }
}

// Fused per-node aggregator (round-0-verified version), software-pipelined:
// while group g runs MFMA/score/softmax/aggregate, the P1 rows of group
// g+gridDim are already in flight into registers (pf). 4 nodes/group,
// 3 barriers/iter.
__global__ __launch_bounds__(256, 2) void agg_kernel(
    const unsigned short* __restrict__ EB, const int* __restrict__ nidx,
    const unsigned short* __restrict__ W2T, const float* __restrict__ b2,
    const float* __restrict__ W3, const float* __restrict__ b3,
    const unsigned short* __restrict__ P1, const unsigned short* __restrict__ Q,
    float* __restrict__ out, int NN)
{
    __shared__ unsigned short sX[128][136];
    __shared__ int   sIdx[128];
    __shared__ float sSp[4][128];
    __shared__ float sAtt[128];

    const int tid  = threadIdx.x;
    const int lane = tid & 63;
    const int w    = tid >> 6;          // wave index == node sub-index
    const int m    = lane & 15, q = lane >> 4;
    const int row  = tid >> 1, half = tid & 1;   // staging role: 2 threads/row

    // register-resident B fragments (W2T), per-wave 32-col slice
    bf16x8 Bf[2][4];
#pragma unroll
    for (int nt = 0; nt < 2; ++nt)
#pragma unroll
        for (int kk = 0; kk < 4; ++kk)
            Bf[nt][kk] = *(const bf16x8*)(W2T + (32 * w + 16 * nt + m) * D + kk * 32 + q * 8);
    float b2v[2], w3v[2];
#pragma unroll
    for (int nt = 0; nt < 2; ++nt) {
        int col = 32 * w + 16 * nt + m;
        b2v[nt] = b2[col];
        w3v[nt] = W3[col];
    }
    const float b3s = b3[0];

    const int groups = (NN + 3) >> 2;

    // ---- pipeline prologue: group blockIdx.x ----
    int g = blockIdx.x;
    int ni_cur = 0;
    bf16x8 pf[8];
    if (g < groups) {
        int nd = g * 4 + (row >> 5); if (nd > NN - 1) nd = NN - 1;
        ni_cur = nidx[nd * KN + (row & 31)];
#pragma unroll
        for (int j = 0; j < 8; ++j)
            pf[j] = *(const bf16x8*)(P1 + (long)ni_cur * D + half * 64 + j * 8);
    }

    for (; g < groups; g += gridDim.x) {
        const int node0 = g * 4;
        int nd = node0 + (row >> 5); if (nd > NN - 1) nd = NN - 1;

        // ---- convert+store X = relu(pf + Q[nd]) ----
        if (half == 0) sIdx[row] = ni_cur;
        {
            const bf16x8* qq = (const bf16x8*)(Q + (long)nd * D) + half * 8;
#pragma unroll
            for (int j = 0; j < 8; ++j) {
                bf16x8 qv = qq[j], r;
#pragma unroll
                for (int h = 0; h < 8; ++h) {
                    float v = bf2f((unsigned short)pf[j][h]) + bf2f((unsigned short)qv[h]);
                    r[h] = (short)f2bf(v > 0.f ? v : 0.f);
                }
                *(bf16x8*)(&sX[row][half * 64 + j * 8]) = r;
            }
        }

        // next-group index load (issue before barrier; independent)
        const int gn = g + gridDim.x;
        const bool more = gn < groups;
        int ni_next = ni_cur;
        if (more) {
            int ndn = gn * 4 + (row >> 5); if (ndn > NN - 1) ndn = NN - 1;
            ni_next = nidx[ndn * KN + (row & 31)];
        }
        __syncthreads();

        // ---- EB prefetch for current group (needs sIdx) ----
        bf16x8 gv[8];
#pragma unroll
        for (int j = 0; j < 8; ++j) {
            int k = (lane >> 4) + 4 * j;
            int ik = sIdx[w * KN + k];
            gv[j] = *(const bf16x8*)(EB + (long)ik * D + (lane & 15) * 8);
        }

        // ---- P1 prefetch for NEXT group (in flight during compute) ----
        if (more) {
#pragma unroll
            for (int j = 0; j < 8; ++j)
                pf[j] = *(const bf16x8*)(P1 + (long)ni_next * D + half * 64 + j * 8);
        }

        // ---- layer-2 GEMM: 8 M-tiles x this wave's 2 N-tiles ----
        f32x4 acc[8][2];
#pragma unroll
        for (int mt = 0; mt < 8; ++mt)
#pragma unroll
            for (int nt = 0; nt < 2; ++nt) acc[mt][nt] = (f32x4){0.f, 0.f, 0.f, 0.f};

#pragma unroll
        for (int kk = 0; kk < 4; ++kk) {
#pragma unroll
            for (int mt = 0; mt < 8; ++mt) {
                bf16x8 a = *(const bf16x8*)(&sX[16 * mt + m][kk * 32 + q * 8]);
                acc[mt][0] = __builtin_amdgcn_mfma_f32_16x16x32_bf16(a, Bf[0][kk], acc[mt][0], 0, 0, 0);
                acc[mt][1] = __builtin_amdgcn_mfma_f32_16x16x32_bf16(a, Bf[1][kk], acc[mt][1], 0, 0, 0);
            }
        }

        // ---- relu+bias, dot W3, reduce across 16 col-lanes ----
#pragma unroll
        for (int mt = 0; mt < 8; ++mt) {
            float p[4];
#pragma unroll
            for (int r = 0; r < 4; ++r) {
                float h0 = acc[mt][0][r] + b2v[0]; h0 = h0 > 0.f ? h0 : 0.f;
                float h1 = acc[mt][1][r] + b2v[1]; h1 = h1 > 0.f ? h1 : 0.f;
                p[r] = h0 * w3v[0] + h1 * w3v[1];
            }
#pragma unroll
            for (int off = 8; off >= 1; off >>= 1)
#pragma unroll
                for (int r = 0; r < 4; ++r) p[r] += __shfl_xor(p[r], off, 16);
            if (m == 0) {
#pragma unroll
                for (int r = 0; r < 4; ++r) sSp[w][16 * mt + 4 * q + r] = p[r];
            }
        }
        __syncthreads();

        // ---- softmax: 128 scores = 4 nodes x 32 neighbors ----
        if (tid < 128) {
            float s = sSp[0][tid] + sSp[1][tid] + sSp[2][tid] + sSp[3][tid] + b3s;
            float mx = s;
#pragma unroll
            for (int off = 16; off >= 1; off >>= 1) mx = fmaxf(mx, __shfl_xor(mx, off, 32));
            float e = __expf(s - mx);
            float sum = e;
#pragma unroll
            for (int off = 16; off >= 1; off >>= 1) sum += __shfl_xor(sum, off, 32);
            sAtt[tid] = e / sum;
        }
        __syncthreads();

        // ---- aggregation: node w per wave, from prefetched gv ----
        {
            float r[8] = {0.f, 0.f, 0.f, 0.f, 0.f, 0.f, 0.f, 0.f};
#pragma unroll
            for (int j = 0; j < 8; ++j) {
                float a = sAtt[w * KN + (lane >> 4) + 4 * j];
#pragma unroll
                for (int h = 0; h < 8; ++h)
                    r[h] += a * bf2f((unsigned short)gv[j][h]);
            }
#pragma unroll
            for (int h = 0; h < 8; ++h) {
                r[h] += __shfl_xor(r[h], 16);
                r[h] += __shfl_xor(r[h], 32);
            }
            int ndw = node0 + w;
            if (lane < 16 && ndw < NN) {
                float4 o0 = {r[0], r[1], r[2], r[3]};
                float4 o1 = {r[4], r[5], r[6], r[7]};
                *(float4*)(out + (long)ndw * D + lane * 8)     = o0;
                *(float4*)(out + (long)ndw * D + lane * 8 + 4) = o1;
            }
        }
        // no 4th barrier needed: next write to sX/sIdx happens after the
        // convert phase, which follows this iteration's barriers; sAtt's
        // next write is 2 barriers away.
        ni_cur = ni_next;
    }
}

// Correct-but-slow fp32 VALU fallback (only if ws is too small).
__global__ __launch_bounds__(128) void naive_kernel(
    const float* __restrict__ emb, const int* __restrict__ vnodes,
    const int* __restrict__ nidx,
    const float* __restrict__ W1, const float* __restrict__ b1,
    const float* __restrict__ W2, const float* __restrict__ b2,
    const float* __restrict__ W3, const float* __restrict__ b3,
    float* __restrict__ out)
{
    __shared__ float sE[KN + 1][D];
    __shared__ float sH[KN][D];
    __shared__ float sH2[KN][D];
    __shared__ float sS[KN];
    __shared__ float sA2[KN];
    const int node = blockIdx.x, tid = threadIdx.x;

    for (int r = 0; r < KN + 1; ++r) {
        int vr = (r < KN) ? nidx[node * KN + r] : vnodes[node];
        sE[r][tid] = emb[(long)vr * D + tid];
    }
    __syncthreads();
    for (int k = 0; k < KN; ++k) {
        float s = b1[tid];
        for (int e = 0; e < D; ++e) s += sE[k][e]  * W1[e * D + tid];
        for (int e = 0; e < D; ++e) s += sE[KN][e] * W1[(D + e) * D + tid];
        sH[k][tid] = s > 0.f ? s : 0.f;
    }
    __syncthreads();
    for (int k = 0; k < KN; ++k) {
        float s = b2[tid];
        for (int e = 0; e < D; ++e) s += sH[k][e] * W2[e * D + tid];
        sH2[k][tid] = s > 0.f ? s : 0.f;
    }
    __syncthreads();
    if (tid < KN) {
        float s = b3[0];
        for (int e = 0; e < D; ++e) s += sH2[tid][e] * W3[e];
        sS[tid] = s;
    }
    __syncthreads();
    if (tid == 0) {
        float mx = sS[0];
        for (int k = 1; k < KN; ++k) mx = fmaxf(mx, sS[k]);
        float sum = 0.f;
        for (int k = 0; k < KN; ++k) { sA2[k] = __expf(sS[k] - mx); sum += sA2[k]; }
        for (int k = 0; k < KN; ++k) sA2[k] /= sum;
    }
    __syncthreads();
    float a = 0.f;
    for (int k = 0; k < KN; ++k) a += sA2[k] * sE[k][tid];
    out[(long)node * D + tid] = a;
}

extern "C" void kernel_launch(void* const* d_in, const int* in_sizes, int n_in,
                              void* d_out, int out_size, void* d_ws, size_t ws_size,
                              hipStream_t stream) {
    const float* emb    = (const float*)d_in[0];
    const int*   vnodes = (const int*)d_in[1];
    const int*   nidx   = (const int*)d_in[2];
    const float* W1     = (const float*)d_in[3];
    const float* b1     = (const float*)d_in[4];
    const float* W2     = (const float*)d_in[5];
    const float* b2     = (const float*)d_in[6];
    const float* W3     = (const float*)d_in[7];
    const float* b3     = (const float*)d_in[8];
    float* out = (float*)d_out;

    const int NV = in_sizes[0] / D;   // 200000
    const int NN = in_sizes[1];       // 20000

    const size_t p1_elems = (size_t)NV * D;
    const size_t q_elems  = (size_t)NN * D;
    const size_t wt_elems = (size_t)D * D;
    const size_t need = (2 * p1_elems + q_elems + 3 * wt_elems) * sizeof(unsigned short);

    if (ws_size >= need) {
        unsigned short* P1   = (unsigned short*)d_ws;
        unsigned short* Q    = P1 + p1_elems;
        unsigned short* W1Tt = Q + q_elems;
        unsigned short* W1Tb = W1Tt + wt_elems;
        unsigned short* W2T  = W1Tb + wt_elems;
        unsigned short* EB   = W2T + wt_elems;

        const int nvBlocks = (NV + 127) / 128;
        const int qBlocks  = (NN + 127) / 128;

        wt_kernel<<<(D * D + 255) / 256, 256, 0, stream>>>(W1, W2, W1Tt, W1Tb, W2T);
        p1q_kernel<<<nvBlocks + qBlocks, 256, 0, stream>>>(
            emb, vnodes, NV, NN, nvBlocks, W1Tt, W1Tb, b1, P1, Q, EB);
        agg_kernel<<<1024, 256, 0, stream>>>(
            EB, nidx, W2T, b2, W3, b3, P1, Q, out, NN);
    } else {
        naive_kernel<<<NN, D, 0, stream>>>(emb, vnodes, nidx, W1, b1, W2, b2, W3, b3, out);
    }
}

// Round 6
// 274.523 us; speedup vs baseline: 1.6682x; 1.0656x over previous
//
#include <hip/hip_runtime.h>
#include <hip/hip_bf16.h>

#define D  128
#define KN 32

typedef __attribute__((ext_vector_type(8))) short bf16x8;
typedef __attribute__((ext_vector_type(4))) float f32x4;

static __device__ __forceinline__ unsigned short f2bf(float f) {
    union { float f; unsigned int u; } v; v.f = f;
    unsigned int u = v.u;
    u += 0x7fff + ((u >> 16) & 1);   // round-to-nearest-even
    return (unsigned short)(u >> 16);
}
static __device__ __forceinline__ float bf2f(unsigned short h) {
    union { float f; unsigned int u; } v; v.u = ((unsigned int)h) << 16;
    return v.f;
}

// One-shot: transpose+convert W1 halves and W2 into bf16 [col][k] layouts.
__global__ __launch_bounds__(256) void wt_kernel(
    const float* __restrict__ W1, const float* __restrict__ W2,
    unsigned short* __restrict__ W1Tt, unsigned short* __restrict__ W1Tb,
    unsigned short* __restrict__ W2T)
{
    int idx = blockIdx.x * 256 + threadIdx.x;
    if (idx < D * D) {
        int col = idx >> 7, e = idx & 127;
        W1Tt[col * D + e] = f2bf(W1[e * D + col]);
        W1Tb[col * D + e] = f2bf(W1[(D + e) * D + col]);
        W2T [col * D + e] = f2bf(W2[e * D + col]);
    }
}

// Fused P1/Q producer (round-3-verified version: restaged epilogue with
// fully-contiguous 4KB-per-instruction stores for EB, P1 and Q).
// Blocks [0,nvBlocks): P1 = emb@W1top (+ bf16 emb copy EB).
// Blocks [nvBlocks,..): Q = emb[vnodes]@W1bot + b1.
__global__ __launch_bounds__(256) void p1q_kernel(
    const float* __restrict__ emb, const int* __restrict__ vnodes,
    int NV, int NN, int nvBlocks,
    const unsigned short* __restrict__ W1Tt, const unsigned short* __restrict__ W1Tb,
    const float* __restrict__ b1,
    unsigned short* __restrict__ P1, unsigned short* __restrict__ Q,
    unsigned short* __restrict__ EB)
{
    __shared__ unsigned short sA[128][136];

    const int tid  = threadIdx.x;
    const int lane = tid & 63;
    const int w    = tid >> 6;
    const int m    = lane & 15, q = lane >> 4;

    const bool nv = (int)blockIdx.x < nvBlocks;
    const int  bi = nv ? blockIdx.x : blockIdx.x - nvBlocks;
    const int  M  = nv ? NV : NN;
    const unsigned short* WT = nv ? W1Tt : W1Tb;
    const int r0 = bi * 128;

    int maxRows = M - r0; if (maxRows > 128) maxRows = 128;
    const int maxB = maxRows << 8;          // valid bytes in this block's region

    // stage 128 rows fp32->bf16 (coalesced float4 stream / gather)
#pragma unroll
    for (int i = 0; i < 16; ++i) {
        int e = tid + 256 * i;
        int row = e >> 5, c4 = (e & 31) << 2;
        int r = r0 + row; if (r > M - 1) r = M - 1;
        int vr = nv ? r : vnodes[r];
        const float4 f = *(const float4*)(emb + (long)vr * D + c4);
        ushort4 h;
        h.x = f2bf(f.x); h.y = f2bf(f.y); h.z = f2bf(f.z); h.w = f2bf(f.w);
        *(ushort4*)(&sA[row][c4]) = h;
    }
    __syncthreads();

    // EB emission (pre-restage sA): fully-contiguous 4KB per instruction
    if (nv) {
        char* ebBase = (char*)(EB + (long)r0 * D);
#pragma unroll
        for (int j = 0; j < 8; ++j) {
            int p = j * 4096 + tid * 16;
            if (p < maxB) {
                int row = p >> 8, off = (p & 255) >> 1;
                *(bf16x8*)(ebBase + p) = *(const bf16x8*)(&sA[row][off]);
            }
        }
    }

    bf16x8 Bf[2][4];
#pragma unroll
    for (int nt = 0; nt < 2; ++nt)
#pragma unroll
        for (int kk = 0; kk < 4; ++kk)
            Bf[nt][kk] = *(const bf16x8*)(WT + (32 * w + 16 * nt + m) * D + kk * 32 + q * 8);
    float bv[2];
#pragma unroll
    for (int nt = 0; nt < 2; ++nt) bv[nt] = nv ? 0.f : b1[32 * w + 16 * nt + m];

    f32x4 acc[8][2];
#pragma unroll
    for (int mt = 0; mt < 8; ++mt)
#pragma unroll
        for (int nt = 0; nt < 2; ++nt) acc[mt][nt] = (f32x4){0.f, 0.f, 0.f, 0.f};

#pragma unroll
    for (int kk = 0; kk < 4; ++kk) {
#pragma unroll
        for (int mt = 0; mt < 8; ++mt) {
            bf16x8 a = *(const bf16x8*)(&sA[16 * mt + m][kk * 32 + q * 8]);
            acc[mt][0] = __builtin_amdgcn_mfma_f32_16x16x32_bf16(a, Bf[0][kk], acc[mt][0], 0, 0, 0);
            acc[mt][1] = __builtin_amdgcn_mfma_f32_16x16x32_bf16(a, Bf[1][kk], acc[mt][1], 0, 0, 0);
        }
    }

    // ---- restage C into sA, then fully-contiguous 4KB stores ----
    __syncthreads();   // all A-reads + EB-reads of sA complete
    // C/D layout: col=lane&15, row=(lane>>4)*4+reg
#pragma unroll
    for (int mt = 0; mt < 8; ++mt)
#pragma unroll
        for (int nt = 0; nt < 2; ++nt) {
            int col = 32 * w + 16 * nt + m;
#pragma unroll
            for (int r = 0; r < 4; ++r)
                sA[16 * mt + 4 * q + r][col] = f2bf(acc[mt][nt][r] + bv[nt]);
        }
    __syncthreads();
    {
        char* dstBase = (char*)((nv ? P1 : Q) + (long)r0 * D);
#pragma unroll
        for (int j = 0; j < 8; ++j) {
            int p = j * 4096 + tid * 16;
            if (p < maxB) {
                int row = p >> 8, off = (p & 255) >> 1;
                *(bf16x8*)(dstBase + p) = *(const bf16x8*)(&sA[row][off]);
            }
        }
    }
}

// Fused per-node aggregator. Round-0 dataflow (4 nodes/group, 3 barriers),
// re-mapped staging roles for coalesced row-gathers:
//   - wave w owns node w of the group; lane (g4 = lane>>4, c = lane&15)
//     handles neighbor k = 4j+g4 (j=0..7), bytes c*16..+16 of each row.
//   - P1 prefetch: 16 lanes/row contiguous -> 4x256B per instruction
//     (was 2 threads/row = 32x32B scattered requests per instruction).
//   - neighbor indices are same-address nidx loads per 16-lane group:
//     sIdx + its barrier dependency are gone; the EB gather issues at
//     iteration TOP with a full iteration of compute to hide under.
//   - layer-2 GEMM runs in 2 halves of 4 M-tiles (32 acc regs, not 64),
//     paying for gv's longer live range without spilling.
__global__ __launch_bounds__(256, 2) void agg_kernel(
    const unsigned short* __restrict__ EB, const int* __restrict__ nidx,
    const unsigned short* __restrict__ W2T, const float* __restrict__ b2,
    const float* __restrict__ W3, const float* __restrict__ b3,
    const unsigned short* __restrict__ P1, const unsigned short* __restrict__ Q,
    float* __restrict__ out, int NN)
{
    __shared__ unsigned short sX[128][136];
    __shared__ float sSp[4][128];
    __shared__ float sAtt[128];

    const int tid  = threadIdx.x;
    const int lane = tid & 63;
    const int w    = tid >> 6;          // wave index == node sub-index
    const int m    = lane & 15, q = lane >> 4;
    const int g4   = q;                 // row-group within wave
    const int c    = m;                 // 16B chunk within row

    // register-resident B fragments (W2T), per-wave 32-col slice
    bf16x8 Bf[2][4];
#pragma unroll
    for (int nt = 0; nt < 2; ++nt)
#pragma unroll
        for (int kk = 0; kk < 4; ++kk)
            Bf[nt][kk] = *(const bf16x8*)(W2T + (32 * w + 16 * nt + m) * D + kk * 32 + q * 8);
    float b2v[2], w3v[2];
#pragma unroll
    for (int nt = 0; nt < 2; ++nt) {
        int col = 32 * w + 16 * nt + m;
        b2v[nt] = b2[col];
        w3v[nt] = W3[col];
    }
    const float b3s = b3[0];

    const int groups = (NN + 3) >> 2;

    // ---- pipeline prologue: group blockIdx.x ----
    int g = blockIdx.x;
    int ni[8];          // neighbor indices, k = 4j+g4 (uniform per 16-lane group)
    bf16x8 pf[8];       // P1 row fragments: pf[j] = P1[ni[j]][c*8 .. +8]
    if (g < groups) {
        int nd = g * 4 + w; if (nd > NN - 1) nd = NN - 1;
#pragma unroll
        for (int j = 0; j < 8; ++j) {
            ni[j] = nidx[nd * KN + 4 * j + g4];
            pf[j] = *(const bf16x8*)(P1 + (long)ni[j] * D + c * 8);
        }
    }

    for (; g < groups; g += gridDim.x) {
        const int node0 = g * 4;
        int nd = node0 + w; if (nd > NN - 1) nd = NN - 1;

        // ---- EB gather for current group at iteration top (4x256B/inst,
        //      consumed at iteration end: full iteration to hide) ----
        bf16x8 gv[8];
#pragma unroll
        for (int j = 0; j < 8; ++j)
            gv[j] = *(const bf16x8*)(EB + (long)ni[j] * D + c * 8);

        // ---- convert+store X = relu(pf + Q[nd]) into wave-private rows ----
        {
            const bf16x8 qv = *(const bf16x8*)(Q + (long)nd * D + c * 8);
#pragma unroll
            for (int j = 0; j < 8; ++j) {
                bf16x8 r;
#pragma unroll
                for (int h = 0; h < 8; ++h) {
                    float v = bf2f((unsigned short)pf[j][h]) + bf2f((unsigned short)qv[h]);
                    r[h] = (short)f2bf(v > 0.f ? v : 0.f);
                }
                *(bf16x8*)(&sX[w * 32 + 4 * j + g4][c * 8]) = r;
            }
        }

        // ---- next-group indices (same-address loads per 16-lane group) ----
        const int gn = g + gridDim.x;
        const bool more = gn < groups;
        int nin[8];
        if (more) {
            int ndn = gn * 4 + w; if (ndn > NN - 1) ndn = NN - 1;
#pragma unroll
            for (int j = 0; j < 8; ++j) nin[j] = nidx[ndn * KN + 4 * j + g4];
        }
        __syncthreads();   // sX ready for all waves

        // ---- P1 prefetch for NEXT group (in flight during compute) ----
        if (more) {
#pragma unroll
            for (int j = 0; j < 8; ++j)
                pf[j] = *(const bf16x8*)(P1 + (long)nin[j] * D + c * 8);
        }

        // ---- layer-2 GEMM in 2 halves of 4 M-tiles (acc = 32 regs) ----
#pragma unroll
        for (int hv = 0; hv < 2; ++hv) {
            f32x4 acc[4][2];
#pragma unroll
            for (int mt = 0; mt < 4; ++mt) {
                acc[mt][0] = (f32x4){0.f, 0.f, 0.f, 0.f};
                acc[mt][1] = (f32x4){0.f, 0.f, 0.f, 0.f};
            }
#pragma unroll
            for (int kk = 0; kk < 4; ++kk) {
#pragma unroll
                for (int mt = 0; mt < 4; ++mt) {
                    bf16x8 a = *(const bf16x8*)(&sX[16 * (4 * hv + mt) + m][kk * 32 + q * 8]);
                    acc[mt][0] = __builtin_amdgcn_mfma_f32_16x16x32_bf16(a, Bf[0][kk], acc[mt][0], 0, 0, 0);
                    acc[mt][1] = __builtin_amdgcn_mfma_f32_16x16x32_bf16(a, Bf[1][kk], acc[mt][1], 0, 0, 0);
                }
            }
            // scores for these 4 M-tiles: relu+bias, dot W3, reduce 16 lanes
#pragma unroll
            for (int mt = 0; mt < 4; ++mt) {
                float p[4];
#pragma unroll
                for (int r = 0; r < 4; ++r) {
                    float h0 = acc[mt][0][r] + b2v[0]; h0 = h0 > 0.f ? h0 : 0.f;
                    float h1 = acc[mt][1][r] + b2v[1]; h1 = h1 > 0.f ? h1 : 0.f;
                    p[r] = h0 * w3v[0] + h1 * w3v[1];
                }
#pragma unroll
                for (int off = 8; off >= 1; off >>= 1)
#pragma unroll
                    for (int r = 0; r < 4; ++r) p[r] += __shfl_xor(p[r], off, 16);
                if (m == 0) {
#pragma unroll
                    for (int r = 0; r < 4; ++r) sSp[w][16 * (4 * hv + mt) + 4 * q + r] = p[r];
                }
            }
        }
        __syncthreads();

        // ---- softmax: 128 scores = 4 nodes x 32 neighbors ----
        if (tid < 128) {
            float s = sSp[0][tid] + sSp[1][tid] + sSp[2][tid] + sSp[3][tid] + b3s;
            float mx = s;
#pragma unroll
            for (int off = 16; off >= 1; off >>= 1) mx = fmaxf(mx, __shfl_xor(mx, off, 32));
            float e = __expf(s - mx);
            float sum = e;
#pragma unroll
            for (int off = 16; off >= 1; off >>= 1) sum += __shfl_xor(sum, off, 32);
            sAtt[tid] = e / sum;
        }
        __syncthreads();

        // ---- aggregation: node w per wave, from top-issued gv ----
        {
            float r8[8] = {0.f, 0.f, 0.f, 0.f, 0.f, 0.f, 0.f, 0.f};
#pragma unroll
            for (int j = 0; j < 8; ++j) {
                float a = sAtt[w * KN + 4 * j + g4];
#pragma unroll
                for (int h = 0; h < 8; ++h)
                    r8[h] += a * bf2f((unsigned short)gv[j][h]);
            }
#pragma unroll
            for (int h = 0; h < 8; ++h) {
                r8[h] += __shfl_xor(r8[h], 16);
                r8[h] += __shfl_xor(r8[h], 32);
            }
            int ndw = node0 + w;
            if (g4 == 0 && ndw < NN) {
                float4 o0 = {r8[0], r8[1], r8[2], r8[3]};
                float4 o1 = {r8[4], r8[5], r8[6], r8[7]};
                *(float4*)(out + (long)ndw * D + c * 8)     = o0;
                *(float4*)(out + (long)ndw * D + c * 8 + 4) = o1;
            }
        }
        // carry next-group indices (safe: loop exits when !more)
#pragma unroll
        for (int j = 0; j < 8; ++j) ni[j] = nin[j];
    }
}

// Correct-but-slow fp32 VALU fallback (only if ws is too small).
__global__ __launch_bounds__(128) void naive_kernel(
    const float* __restrict__ emb, const int* __restrict__ vnodes,
    const int* __restrict__ nidx,
    const float* __restrict__ W1, const float* __restrict__ b1,
    const float* __restrict__ W2, const float* __restrict__ b2,
    const float* __restrict__ W3, const float* __restrict__ b3,
    float* __restrict__ out)
{
    __shared__ float sE[KN + 1][D];
    __shared__ float sH[KN][D];
    __shared__ float sH2[KN][D];
    __shared__ float sS[KN];
    __shared__ float sA2[KN];
    const int node = blockIdx.x, tid = threadIdx.x;

    for (int r = 0; r < KN + 1; ++r) {
        int vr = (r < KN) ? nidx[node * KN + r] : vnodes[node];
        sE[r][tid] = emb[(long)vr * D + tid];
    }
    __syncthreads();
    for (int k = 0; k < KN; ++k) {
        float s = b1[tid];
        for (int e = 0; e < D; ++e) s += sE[k][e]  * W1[e * D + tid];
        for (int e = 0; e < D; ++e) s += sE[KN][e] * W1[(D + e) * D + tid];
        sH[k][tid] = s > 0.f ? s : 0.f;
    }
    __syncthreads();
    for (int k = 0; k < KN; ++k) {
        float s = b2[tid];
        for (int e = 0; e < D; ++e) s += sH[k][e] * W2[e * D + tid];
        sH2[k][tid] = s > 0.f ? s : 0.f;
    }
    __syncthreads();
    if (tid < KN) {
        float s = b3[0];
        for (int e = 0; e < D; ++e) s += sH2[tid][e] * W3[e];
        sS[tid] = s;
    }
    __syncthreads();
    if (tid == 0) {
        float mx = sS[0];
        for (int k = 1; k < KN; ++k) mx = fmaxf(mx, sS[k]);
        float sum = 0.f;
        for (int k = 0; k < KN; ++k) { sA2[k] = __expf(sS[k] - mx); sum += sA2[k]; }
        for (int k = 0; k < KN; ++k) sA2[k] /= sum;
    }
    __syncthreads();
    float a = 0.f;
    for (int k = 0; k < KN; ++k) a += sA2[k] * sE[k][tid];
    out[(long)node * D + tid] = a;
}

extern "C" void kernel_launch(void* const* d_in, const int* in_sizes, int n_in,
                              void* d_out, int out_size, void* d_ws, size_t ws_size,
                              hipStream_t stream) {
    const float* emb    = (const float*)d_in[0];
    const int*   vnodes = (const int*)d_in[1];
    const int*   nidx   = (const int*)d_in[2];
    const float* W1     = (const float*)d_in[3];
    const float* b1     = (const float*)d_in[4];
    const float* W2     = (const float*)d_in[5];
    const float* b2     = (const float*)d_in[6];
    const float* W3     = (const float*)d_in[7];
    const float* b3     = (const float*)d_in[8];
    float* out = (float*)d_out;

    const int NV = in_sizes[0] / D;   // 200000
    const int NN = in_sizes[1];       // 20000

    const size_t p1_elems = (size_t)NV * D;
    const size_t q_elems  = (size_t)NN * D;
    const size_t wt_elems = (size_t)D * D;
    const size_t need = (2 * p1_elems + q_elems + 3 * wt_elems) * sizeof(unsigned short);

    if (ws_size >= need) {
        unsigned short* P1   = (unsigned short*)d_ws;
        unsigned short* Q    = P1 + p1_elems;
        unsigned short* W1Tt = Q + q_elems;
        unsigned short* W1Tb = W1Tt + wt_elems;
        unsigned short* W2T  = W1Tb + wt_elems;
        unsigned short* EB   = W2T + wt_elems;

        const int nvBlocks = (NV + 127) / 128;
        const int qBlocks  = (NN + 127) / 128;

        wt_kernel<<<(D * D + 255) / 256, 256, 0, stream>>>(W1, W2, W1Tt, W1Tb, W2T);
        p1q_kernel<<<nvBlocks + qBlocks, 256, 0, stream>>>(
            emb, vnodes, NV, NN, nvBlocks, W1Tt, W1Tb, b1, P1, Q, EB);
        agg_kernel<<<1024, 256, 0, stream>>>(
            EB, nidx, W2T, b2, W3, b3, P1, Q, out, NN);
    } else {
        naive_kernel<<<NN, D, 0, stream>>>(emb, vnodes, nidx, W1, b1, W2, b2, W3, b3, out);
    }
}